// Round 11
// baseline (899.760 us; speedup 1.0000x reference)
//
#include <hip/hip_runtime.h>

#define DD 128
#define HH 512
#define WW 512
#define NVOX (DD*HH*WW)          // 33554432
#define THRESHV 0.997f
#define KPEAKS 131072
#define PEAK_CAP (1u<<18)        // 262144 peak slots (expect ~63K)
#define NBINS 65536

// peaks all lie in (0.997, 1.0): float bits have constant upper 16 bits
// 0x3F7F -> low 16 bits monotone in value. bin=(~bits)&0xFFFF so ascending
// bin == descending value. Exact-value ties are COMMON -> tie-fix required.

// ---------------- K0: init scratch (ws is poisoned 0xAA before every call).
__global__ void k_init(unsigned* counters, unsigned* hist) {
    unsigned t = blockIdx.x * 1024u + threadIdx.x;
    if (t < 64) counters[t] = 0u;
    if (t < NBINS) hist[t] = 0u;
}

// ---------------- K1: WAVE-AUTONOMOUS scan + verify. 256 thr x 8192 blk.
// R19: the convoy-breaker. Evidence: R15 (scan 50 + verify 34 = 84 exactly,
// zero overlap), R17/R18 (time independent of data tier AND of load path;
// VALU 19% / HBM 15% both idle) -> k_find is bound by lockstep latency
// convoys created by intra-block barriers. This kernel has NO __syncthreads
// and NO LDS: each wave owns 1024 voxels (4 float4/thread), scans in
// registers, then verifies ITS OWN candidates via a uniform ballot loop,
// pushing survivors straight to global. Waves de-phase freely; scan-wait
// overlaps verify-wait across the 32 waves/CU. Locality preserved: wave
// strips are contiguous; z+-k planes are block+-64k == same XCD (mod 8);
// concurrent scan footprint 32x4KB x 32CU = 4MB/XCD = L2 budget.
__global__ __launch_bounds__(256, 8)
void k_find(const float4* __restrict__ vol4, const float* __restrict__ vol,
            unsigned* counters, unsigned* hist,
            unsigned long long* keys, float4* psums) {
    unsigned t = threadIdx.x;
    unsigned lane = t & 63u;
    unsigned w = t >> 6;                      // wave id 0..3 (wave-uniform)
    unsigned wb4 = blockIdx.x * 1024u + w * 256u;  // wave's float4 base
    int dz = (int)lane / 7, dy = (int)lane - dz * 7;   // meaningful for lane<49

    // ---- scan: 4 independent float4 loads (1KB/wave each, coalesced)
    float4 a0 = vol4[wb4 + lane];
    float4 a1 = vol4[wb4 + 64u + lane];
    float4 a2 = vol4[wb4 + 128u + lane];
    float4 a3 = vol4[wb4 + 192u + lane];
    __builtin_amdgcn_sched_barrier(0);        // all 4 issued before any use
    unsigned m = 0u;
    m |= (a0.x > THRESHV ? 1u : 0u);
    m |= (a0.y > THRESHV ? 2u : 0u);
    m |= (a0.z > THRESHV ? 4u : 0u);
    m |= (a0.w > THRESHV ? 8u : 0u);
    m |= (a1.x > THRESHV ? 16u : 0u);
    m |= (a1.y > THRESHV ? 32u : 0u);
    m |= (a1.z > THRESHV ? 64u : 0u);
    m |= (a1.w > THRESHV ? 128u : 0u);
    m |= (a2.x > THRESHV ? 256u : 0u);
    m |= (a2.y > THRESHV ? 512u : 0u);
    m |= (a2.z > THRESHV ? 1024u : 0u);
    m |= (a2.w > THRESHV ? 2048u : 0u);
    m |= (a3.x > THRESHV ? 4096u : 0u);
    m |= (a3.y > THRESHV ? 8192u : 0u);
    m |= (a3.z > THRESHV ? 16384u : 0u);
    m |= (a3.w > THRESHV ? 32768u : 0u);

    // ---- verify: one candidate per iteration, whole wave participates.
    // Uniform ballot loop: pick first lane with a pending bit, broadcast its
    // mask, clear that bit, verify that voxel. Terminates after exactly
    // (total candidate bits in wave) iterations (~3 expected).
    unsigned long long act = __ballot(m != 0u);
    while (act) {
        unsigned src = (unsigned)(__ffsll((unsigned long long)act) - 1);
        unsigned msrc = __shfl(m, (int)src);
        unsigned b = (unsigned)(__ffs(msrc) - 1);
        if (lane == src) m &= (m - 1u);
        unsigned f4 = wb4 + (b >> 2) * 64u + src;
        unsigned idx = f4 * 4u + (b & 3u);    // wave-uniform candidate voxel

        int z = (int)(idx >> 18), y = (int)((idx >> 9) & 511), x = (int)(idx & 511);
        int nz = z + dz - 3, ny = y + dy - 3;
        bool rowok = (lane < 49) && ((unsigned)nz < DD) && ((unsigned)ny < HH);
        size_t rb = rowok ? (((size_t)(unsigned)nz << 18) | ((size_t)(unsigned)ny << 9))
                          : (((size_t)z << 18) | ((size_t)y << 9));
        float rv[7];
        bool interior = (x >= 3) && (x <= WW - 4);   // wave-uniform branch
        if (interior) {
            float4 f0 = *(const float4*)(vol + rb + (unsigned)(x - 3));
            float4 f1 = *(const float4*)(vol + rb + (unsigned)(x + 1));
            rv[0] = f0.x; rv[1] = f0.y; rv[2] = f0.z; rv[3] = f0.w;
            rv[4] = f1.x; rv[5] = f1.y; rv[6] = f1.z;
        } else {
            // rare x-edge path (wave-uniform): clamped scalar loads
#pragma unroll
            for (int d = 0; d < 7; d++) {
                int nx = x + d - 3;
                bool ok = (unsigned)nx < WW;
                float v = vol[rb + (unsigned)(ok ? nx : x)];
                rv[d] = ok ? v : 0.f;
            }
        }
        if (!rowok) {
#pragma unroll
            for (int d = 0; d < 7; d++) rv[d] = 0.f;
        }
        float center = __shfl(rv[3], 24);     // lane 24 = (dz=3,dy=3), elem 3

        bool kill = false;
        float s0r = 0.f, sxr = 0.f;
#pragma unroll
        for (int d = 0; d < 7; d++) {
            kill |= rv[d] > center;
            s0r += rv[d];
            sxr += rv[d] * (float)(d - 3);
        }
        if (!__any(kill)) {
            float s0 = s0r, sx = sxr;
            float sy = s0r * (float)(dy - 3);
            float sz = s0r * (float)(dz - 3);
            for (int off = 32; off; off >>= 1) {
                s0 += __shfl_down(s0, off);
                sx += __shfl_down(sx, off);
                sy += __shfl_down(sy, off);
                sz += __shfl_down(sz, off);
            }
            if (lane == 0) {
                unsigned bits = __float_as_uint(center);
                atomicAdd(&hist[(~bits) & 0xFFFFu], 1u);
                unsigned slot = atomicAdd(&counters[1], 1u);
                if (slot < PEAK_CAP) {
                    keys[slot] = ((unsigned long long)bits << 32) | idx;
                    psums[slot] = make_float4(s0, sx, sy, sz);
                }
            }
        }
        act = __ballot(m != 0u);
    }
}

// ---------------- K2: parallel scan, stage 1. 256 blocks x 256 thr.
// Each block scans its 256-bin chunk; cursor gets the block-LOCAL exclusive
// prefix; blocksum gets the chunk total. Stage 2 is fused into k_scatter.
__global__ void k_scan_a(const unsigned* __restrict__ hist,
                         unsigned* __restrict__ cursor,
                         unsigned* __restrict__ blocksum) {
    __shared__ unsigned sc[256];
    unsigned t = threadIdx.x, b = blockIdx.x;
    unsigned h = hist[b * 256u + t];
    sc[t] = h;
    __syncthreads();
    for (unsigned off = 1u; off < 256u; off <<= 1) {
        unsigned v = (t >= off) ? sc[t - off] : 0u;
        __syncthreads();
        sc[t] += v;
        __syncthreads();
    }
    cursor[b * 256u + t] = sc[t] - h;         // block-local exclusive
    if (t == 255u) blocksum[b] = sc[255];
}

// ---------------- K3: scatter (with scan stage-2 fused). Each block first
// scans the 256 chunk totals in LDS (1KB, L2-hot), then final position =
// chunk_base[bin>>8] + atomicAdd(cursor[bin]) where cursor holds the
// block-local prefix -- algebraically identical to the old scan_b+scatter.
__global__ void k_scatter(const unsigned* __restrict__ counters,
                          const unsigned long long* __restrict__ keys,
                          const unsigned* __restrict__ blocksum,
                          unsigned* cursor, unsigned long long* sorted,
                          unsigned* sslot,
                          float4* __restrict__ out, float* __restrict__ valid) {
    __shared__ unsigned bs[256];
    unsigned t = threadIdx.x;
    if (t < 256u) bs[t] = blocksum[t];
    __syncthreads();
    for (unsigned off = 1u; off < 256u; off <<= 1) {
        unsigned v = (t < 256u && t >= off) ? bs[t - off] : 0u;
        __syncthreads();
        if (t < 256u) bs[t] += v;
        __syncthreads();
    }
    unsigned np = counters[1]; if (np > PEAK_CAP) np = PEAK_CAP;
    unsigned g = blockIdx.x * 1024u + t;
    if (g < np) {
        unsigned long long key = keys[g];
        unsigned bits = (unsigned)(key >> 32);
        unsigned bin = (~bits) & 0xFFFFu;
        unsigned c = bin >> 8;
        unsigned base_c = (c > 0u) ? bs[c - 1u] : 0u;
        unsigned pos = base_c + atomicAdd(&cursor[bin], 1u);
        if (pos < PEAK_CAP) { sorted[pos] = key; sslot[pos] = g; }
    } else if (g < KPEAKS) {
        out[g] = make_float4(0.f, 0.f, 0.f, 0.f);
        valid[g] = 0.f;
    }
}

// ---------------- K4: tiefix + output fused.
__global__ void k_finish(const unsigned* __restrict__ counters,
                         const unsigned long long* __restrict__ sorted,
                         const unsigned* __restrict__ sslot,
                         const float4* __restrict__ psums,
                         float4* __restrict__ out, float* __restrict__ valid) {
    unsigned np = counters[1]; if (np > PEAK_CAP) np = PEAK_CAP;
    unsigned t = blockIdx.x * 1024u + threadIdx.x;
    if (t >= np) return;
    unsigned long long key = sorted[t];
    unsigned bits = (unsigned)(key >> 32);
    unsigned s = t;
    while (s > 0 && (unsigned)(sorted[s - 1] >> 32) == bits) s--;
    unsigned myidx = (unsigned)key;
    unsigned rank = 0, e = s;
    while (e < np) {
        unsigned long long k2 = sorted[e];
        if ((unsigned)(k2 >> 32) != bits) break;
        if ((unsigned)k2 < myidx) rank++;
        e++;
    }
    unsigned row = s + rank;
    if (row >= KPEAKS) return;
    unsigned idx = myidx;
    int z = idx >> 18, y = (idx >> 9) & 511, x = idx & 511;
    float4 ps = psums[sslot[t]];
    float val = __uint_as_float(bits);
    float xloc = ps.y / ps.x, yloc = ps.z / ps.x, zloc = ps.w / ps.x;
    float xr = ((float)x + xloc - (float)(WW - 1) * 0.5f) * 0.1f;
    float yr = ((float)y + yloc - (float)(HH - 1) * 0.5f) * 0.1f;
    float zr = ((float)z + zloc + 0.5f) * 0.02f - 2.0f;
    out[row] = make_float4(xr, yr, zr, val);
    valid[row] = 1.f;
}

extern "C" void kernel_launch(void* const* d_in, const int* in_sizes, int n_in,
                              void* d_out, int out_size, void* d_ws, size_t ws_size,
                              hipStream_t stream) {
    const float* vol = (const float*)d_in[0];
    // d_in[1] = max_peaks scalar (device); fixed at 131072 for this problem.

    char* w = (char*)d_ws;
    unsigned* counters = (unsigned*)w;                                   // 1 KB
    unsigned* hist     = (unsigned*)(w + 1024);                          // 256 KB
    unsigned* cursor   = (unsigned*)(w + 1024 + NBINS * 4);              // 256 KB
    char* w2 = w + 1024 + 2 * NBINS * 4;
    unsigned long long* keys   = (unsigned long long*)w2;                // 2 MB
    unsigned long long* sorted = keys + PEAK_CAP;                        // 2 MB
    unsigned* sslot = (unsigned*)(sorted + PEAK_CAP);                    // 1 MB
    float4*   psums = (float4*)(sslot + PEAK_CAP);                       // 4 MB
    unsigned* blocksum = (unsigned*)(psums + PEAK_CAP);                  // 1 KB
    // total ~9.5 MB of ws. blocksum dedicated (fused k_scatter reads it
    // while writing sslot -- aliasing them would be a race).

    float* out_rows = (float*)d_out;                 // (131072, 4)
    float* valid = out_rows + (size_t)KPEAKS * 4;    // (131072,)

    k_init<<<NBINS / 1024, 1024, 0, stream>>>(counters, hist);
    k_find<<<NVOX / 4096, 256, 0, stream>>>((const float4*)vol, vol, counters, hist, keys, psums);
    k_scan_a<<<256, 256, 0, stream>>>(hist, cursor, blocksum);
    k_scatter<<<PEAK_CAP / 1024, 1024, 0, stream>>>(counters, keys, blocksum, cursor,
                                                    sorted, sslot,
                                                    (float4*)out_rows, valid);
    k_finish<<<PEAK_CAP / 1024, 1024, 0, stream>>>(counters, sorted, sslot, psums,
                                                   (float4*)out_rows, valid);
}

// Round 12
// 237.846 us; speedup vs baseline: 3.7830x; 3.7830x over previous
//
#include <hip/hip_runtime.h>

#define DD 128
#define HH 512
#define WW 512
#define NVOX (DD*HH*WW)          // 33554432
#define THRESHV 0.997f
#define KPEAKS 131072
#define PEAK_CAP (1u<<18)        // 262144 peak slots (expect ~63K)
#define NBINS 65536

// peaks all lie in (0.997, 1.0): float bits have constant upper 16 bits
// 0x3F7F -> low 16 bits monotone in value. bin=(~bits)&0xFFFF so ascending
// bin == descending value. Exact-value ties are COMMON -> tie-fix required.

// ---------------- K0: init scratch (ws is poisoned 0xAA before every call).
__global__ void k_init(unsigned* counters, unsigned* hist) {
    unsigned t = blockIdx.x * 1024u + threadIdx.x;
    if (t < 64) counters[t] = 0u;
    if (t < NBINS) hist[t] = 0u;
}

// ---------------- K1: wave-autonomous scan+verify, block-staged survivors.
// 512 thr x 4096 blk. R20 = the decontaminated convoy test:
//  - R18 geometry: 8192-voxel slab, 4 blocks/CU -> 4MB/XCD L2 footprint
//    (FETCH 92MB pedigree), z+-3 neighbors same-XCD.
//  - R19 wave autonomy: each of 8 waves owns 1024 voxels; register scan;
//    ballot-loop verify of its OWN candidates; NO barriers until flush ->
//    waves de-phase, scan-wait overlaps verify-wait across 32 waves/CU.
//  - R0 survivor staging: LDS atomic slot (ds_add_rtn, ~20cy) + ONE global
//    counters[1] atomic per block. R19's fatal 63K same-address returning
//    global atomics (28cy serialized each = 730us) are gone.
__global__ __launch_bounds__(512, 8)
void k_find(const float4* __restrict__ vol4, const float* __restrict__ vol,
            unsigned* counters, unsigned* hist,
            unsigned long long* keys, float4* psums) {
    __shared__ unsigned pcnt, lbase;
    __shared__ unsigned long long lbuf[192];  // surviving peak keys (E~16)
    __shared__ float4 sbuf[192];              // surviving centroid sums
    if (threadIdx.x == 0) pcnt = 0;
    __syncthreads();

    unsigned t = threadIdx.x;
    unsigned lane = t & 63u;
    unsigned w = t >> 6;                      // wave id 0..7 (wave-uniform)
    unsigned wb4 = blockIdx.x * 2048u + w * 256u;  // wave's 1024-voxel strip
    int dz = (int)lane / 7, dy = (int)lane - dz * 7;   // meaningful for lane<49

    // ---- scan: 4 independent float4 loads (1KB/wave each, coalesced)
    float4 a0 = vol4[wb4 + lane];
    float4 a1 = vol4[wb4 + 64u + lane];
    float4 a2 = vol4[wb4 + 128u + lane];
    float4 a3 = vol4[wb4 + 192u + lane];
    __builtin_amdgcn_sched_barrier(0);        // all 4 issued before any use
    unsigned m = 0u;
    m |= (a0.x > THRESHV ? 1u : 0u);
    m |= (a0.y > THRESHV ? 2u : 0u);
    m |= (a0.z > THRESHV ? 4u : 0u);
    m |= (a0.w > THRESHV ? 8u : 0u);
    m |= (a1.x > THRESHV ? 16u : 0u);
    m |= (a1.y > THRESHV ? 32u : 0u);
    m |= (a1.z > THRESHV ? 64u : 0u);
    m |= (a1.w > THRESHV ? 128u : 0u);
    m |= (a2.x > THRESHV ? 256u : 0u);
    m |= (a2.y > THRESHV ? 512u : 0u);
    m |= (a2.z > THRESHV ? 1024u : 0u);
    m |= (a2.w > THRESHV ? 2048u : 0u);
    m |= (a3.x > THRESHV ? 4096u : 0u);
    m |= (a3.y > THRESHV ? 8192u : 0u);
    m |= (a3.z > THRESHV ? 16384u : 0u);
    m |= (a3.w > THRESHV ? 32768u : 0u);

    // ---- verify: one candidate per wave-iteration (ballot-uniform loop,
    // body proven in R19). ~3 iterations expected per wave.
    unsigned long long act = __ballot(m != 0u);
    while (act) {
        unsigned src = (unsigned)(__ffsll((unsigned long long)act) - 1);
        unsigned msrc = __shfl(m, (int)src);
        unsigned b = (unsigned)(__ffs(msrc) - 1);
        if (lane == src) m &= (m - 1u);
        unsigned f4 = wb4 + (b >> 2) * 64u + src;
        unsigned idx = f4 * 4u + (b & 3u);    // wave-uniform candidate voxel

        int z = (int)(idx >> 18), y = (int)((idx >> 9) & 511), x = (int)(idx & 511);
        int nz = z + dz - 3, ny = y + dy - 3;
        bool rowok = (lane < 49) && ((unsigned)nz < DD) && ((unsigned)ny < HH);
        size_t rb = rowok ? (((size_t)(unsigned)nz << 18) | ((size_t)(unsigned)ny << 9))
                          : (((size_t)z << 18) | ((size_t)y << 9));
        float rv[7];
        bool interior = (x >= 3) && (x <= WW - 4);   // wave-uniform branch
        if (interior) {
            float4 f0 = *(const float4*)(vol + rb + (unsigned)(x - 3));
            float4 f1 = *(const float4*)(vol + rb + (unsigned)(x + 1));
            rv[0] = f0.x; rv[1] = f0.y; rv[2] = f0.z; rv[3] = f0.w;
            rv[4] = f1.x; rv[5] = f1.y; rv[6] = f1.z;
        } else {
            // rare x-edge path (wave-uniform): clamped scalar loads
#pragma unroll
            for (int d = 0; d < 7; d++) {
                int nx = x + d - 3;
                bool ok = (unsigned)nx < WW;
                float v = vol[rb + (unsigned)(ok ? nx : x)];
                rv[d] = ok ? v : 0.f;
            }
        }
        if (!rowok) {
#pragma unroll
            for (int d = 0; d < 7; d++) rv[d] = 0.f;
        }
        float center = __shfl(rv[3], 24);     // lane 24 = (dz=3,dy=3), elem 3

        bool kill = false;
        float s0r = 0.f, sxr = 0.f;
#pragma unroll
        for (int d = 0; d < 7; d++) {
            kill |= rv[d] > center;
            s0r += rv[d];
            sxr += rv[d] * (float)(d - 3);
        }
        if (!__any(kill)) {
            float s0 = s0r, sx = sxr;
            float sy = s0r * (float)(dy - 3);
            float sz = s0r * (float)(dz - 3);
            for (int off = 32; off; off >>= 1) {
                s0 += __shfl_down(s0, off);
                sx += __shfl_down(sx, off);
                sy += __shfl_down(sy, off);
                sz += __shfl_down(sz, off);
            }
            if (lane == 0) {
                unsigned bits = __float_as_uint(center);
                atomicAdd(&hist[(~bits) & 0xFFFFu], 1u);   // spread bins
                unsigned li = atomicAdd(&pcnt, 1u);        // LDS atomic, fast
                if (li < 192u) {
                    lbuf[li] = ((unsigned long long)bits << 32) | idx;
                    sbuf[li] = make_float4(s0, sx, sy, sz);
                }
            }
        }
        act = __ballot(m != 0u);
    }

    // ---- flush: one global atomic per block (R0's proven pattern)
    __syncthreads();
    if (threadIdx.x == 0) lbase = atomicAdd(&counters[1], pcnt);
    __syncthreads();
    unsigned np = pcnt > 192u ? 192u : pcnt;
    for (unsigned i = threadIdx.x; i < np; i += 512u) {
        unsigned p = lbase + i;
        if (p < PEAK_CAP) { keys[p] = lbuf[i]; psums[p] = sbuf[i]; }
    }
}

// ---------------- K2: parallel scan, stage 1. 256 blocks x 256 thr.
// Each block scans its 256-bin chunk; cursor gets the block-LOCAL exclusive
// prefix; blocksum gets the chunk total. Stage 2 is fused into k_scatter.
__global__ void k_scan_a(const unsigned* __restrict__ hist,
                         unsigned* __restrict__ cursor,
                         unsigned* __restrict__ blocksum) {
    __shared__ unsigned sc[256];
    unsigned t = threadIdx.x, b = blockIdx.x;
    unsigned h = hist[b * 256u + t];
    sc[t] = h;
    __syncthreads();
    for (unsigned off = 1u; off < 256u; off <<= 1) {
        unsigned v = (t >= off) ? sc[t - off] : 0u;
        __syncthreads();
        sc[t] += v;
        __syncthreads();
    }
    cursor[b * 256u + t] = sc[t] - h;         // block-local exclusive
    if (t == 255u) blocksum[b] = sc[255];
}

// ---------------- K3: scatter (with scan stage-2 fused). Each block first
// scans the 256 chunk totals in LDS (1KB, L2-hot), then final position =
// chunk_base[bin>>8] + atomicAdd(cursor[bin]) where cursor holds the
// block-local prefix -- algebraically identical to the old scan_b+scatter.
__global__ void k_scatter(const unsigned* __restrict__ counters,
                          const unsigned long long* __restrict__ keys,
                          const unsigned* __restrict__ blocksum,
                          unsigned* cursor, unsigned long long* sorted,
                          unsigned* sslot,
                          float4* __restrict__ out, float* __restrict__ valid) {
    __shared__ unsigned bs[256];
    unsigned t = threadIdx.x;
    if (t < 256u) bs[t] = blocksum[t];
    __syncthreads();
    for (unsigned off = 1u; off < 256u; off <<= 1) {
        unsigned v = (t < 256u && t >= off) ? bs[t - off] : 0u;
        __syncthreads();
        if (t < 256u) bs[t] += v;
        __syncthreads();
    }
    unsigned np = counters[1]; if (np > PEAK_CAP) np = PEAK_CAP;
    unsigned g = blockIdx.x * 1024u + t;
    if (g < np) {
        unsigned long long key = keys[g];
        unsigned bits = (unsigned)(key >> 32);
        unsigned bin = (~bits) & 0xFFFFu;
        unsigned c = bin >> 8;
        unsigned base_c = (c > 0u) ? bs[c - 1u] : 0u;
        unsigned pos = base_c + atomicAdd(&cursor[bin], 1u);
        if (pos < PEAK_CAP) { sorted[pos] = key; sslot[pos] = g; }
    } else if (g < KPEAKS) {
        out[g] = make_float4(0.f, 0.f, 0.f, 0.f);
        valid[g] = 0.f;
    }
}

// ---------------- K4: tiefix + output fused.
__global__ void k_finish(const unsigned* __restrict__ counters,
                         const unsigned long long* __restrict__ sorted,
                         const unsigned* __restrict__ sslot,
                         const float4* __restrict__ psums,
                         float4* __restrict__ out, float* __restrict__ valid) {
    unsigned np = counters[1]; if (np > PEAK_CAP) np = PEAK_CAP;
    unsigned t = blockIdx.x * 1024u + threadIdx.x;
    if (t >= np) return;
    unsigned long long key = sorted[t];
    unsigned bits = (unsigned)(key >> 32);
    unsigned s = t;
    while (s > 0 && (unsigned)(sorted[s - 1] >> 32) == bits) s--;
    unsigned myidx = (unsigned)key;
    unsigned rank = 0, e = s;
    while (e < np) {
        unsigned long long k2 = sorted[e];
        if ((unsigned)(k2 >> 32) != bits) break;
        if ((unsigned)k2 < myidx) rank++;
        e++;
    }
    unsigned row = s + rank;
    if (row >= KPEAKS) return;
    unsigned idx = myidx;
    int z = idx >> 18, y = (idx >> 9) & 511, x = idx & 511;
    float4 ps = psums[sslot[t]];
    float val = __uint_as_float(bits);
    float xloc = ps.y / ps.x, yloc = ps.z / ps.x, zloc = ps.w / ps.x;
    float xr = ((float)x + xloc - (float)(WW - 1) * 0.5f) * 0.1f;
    float yr = ((float)y + yloc - (float)(HH - 1) * 0.5f) * 0.1f;
    float zr = ((float)z + zloc + 0.5f) * 0.02f - 2.0f;
    out[row] = make_float4(xr, yr, zr, val);
    valid[row] = 1.f;
}

extern "C" void kernel_launch(void* const* d_in, const int* in_sizes, int n_in,
                              void* d_out, int out_size, void* d_ws, size_t ws_size,
                              hipStream_t stream) {
    const float* vol = (const float*)d_in[0];
    // d_in[1] = max_peaks scalar (device); fixed at 131072 for this problem.

    char* w = (char*)d_ws;
    unsigned* counters = (unsigned*)w;                                   // 1 KB
    unsigned* hist     = (unsigned*)(w + 1024);                          // 256 KB
    unsigned* cursor   = (unsigned*)(w + 1024 + NBINS * 4);              // 256 KB
    char* w2 = w + 1024 + 2 * NBINS * 4;
    unsigned long long* keys   = (unsigned long long*)w2;                // 2 MB
    unsigned long long* sorted = keys + PEAK_CAP;                        // 2 MB
    unsigned* sslot = (unsigned*)(sorted + PEAK_CAP);                    // 1 MB
    float4*   psums = (float4*)(sslot + PEAK_CAP);                       // 4 MB
    unsigned* blocksum = (unsigned*)(psums + PEAK_CAP);                  // 1 KB
    // total ~9.5 MB of ws. blocksum dedicated (fused k_scatter reads it
    // while writing sslot -- aliasing them would be a race).

    float* out_rows = (float*)d_out;                 // (131072, 4)
    float* valid = out_rows + (size_t)KPEAKS * 4;    // (131072,)

    k_init<<<NBINS / 1024, 1024, 0, stream>>>(counters, hist);
    k_find<<<NVOX / 8192, 512, 0, stream>>>((const float4*)vol, vol, counters, hist, keys, psums);
    k_scan_a<<<256, 256, 0, stream>>>(hist, cursor, blocksum);
    k_scatter<<<PEAK_CAP / 1024, 1024, 0, stream>>>(counters, keys, blocksum, cursor,
                                                    sorted, sslot,
                                                    (float4*)out_rows, valid);
    k_finish<<<PEAK_CAP / 1024, 1024, 0, stream>>>(counters, sorted, sslot, psums,
                                                   (float4*)out_rows, valid);
}